// Round 1
// baseline (664.831 us; speedup 1.0000x reference)
//
#include <hip/hip_runtime.h>
#include <math.h>

// Problem constants (B,C,H,W = 4,96,96,96)
#define kC    96
#define kL    9216          // H*W
#define kB    4
#define kDI   192           // d_inner
#define kDS   16            // d_state
#define kDTR  6             // dt_rank
#define kCL   128           // scan chunk length
#define kNC   72            // chunks per sequence (72*128 = 9216)
#define kNROW (kB*kL)       // 36864 rows
#define kNSEQ (kB*kDI*kDS)  // 12288 independent scalar recurrences

__device__ __forceinline__ float silu_f(float v) { return v / (1.f + expf(-v)); }

// ---------------------------------------------------------------------------
// K0: precompute WcT[k][co] = sum_c in_proj_w[co][c]*proj_w[c][k]  (k<192, co<384)
//     bias_c[co] = in_proj_w[co] . proj_b ;  A[d][s] = -exp(A_log[d][s])
// ---------------------------------------------------------------------------
__global__ __launch_bounds__(256)
void k0_prep(const float* __restrict__ proj_w, const float* __restrict__ proj_b,
             const float* __restrict__ in_proj_w, const float* __restrict__ A_log,
             float* __restrict__ WcT, float* __restrict__ bias_c, float* __restrict__ A)
{
    int idx = blockIdx.x * 256 + threadIdx.x;
    if (idx < 384 * 192) {
        int co = idx / 192;
        int k  = idx % 192;
        float acc = 0.f;
        #pragma unroll 4
        for (int c = 0; c < 96; ++c)
            acc += in_proj_w[co * 96 + c] * proj_w[c * 192 + k];
        WcT[k * 384 + co] = acc;
    }
    if (idx < 384) {
        float acc = 0.f;
        for (int c = 0; c < 96; ++c) acc += in_proj_w[idx * 96 + c] * proj_b[c];
        bias_c[idx] = acc;
    }
    if (idx < kDI * kDS) {
        A[idx] = -expf(A_log[idx]);
    }
}

// ---------------------------------------------------------------------------
// K1: xz = seq @ WcT + bias.  seq[b,l,k] = spatial[b,k,l] (k<96) / freq (k>=96)
// Writes x_in[b*L+l][192] and z[b*L+l][192].
// Block: 384 threads (one per output col), 16 l-rows per block, seq tile in LDS.
// ---------------------------------------------------------------------------
__global__ __launch_bounds__(384)
void k1_xz(const float* __restrict__ spatial, const float* __restrict__ freq,
           const float* __restrict__ WcT, const float* __restrict__ bias_c,
           float* __restrict__ x_in, float* __restrict__ z)
{
    __shared__ float sq[192 * 16];
    const int t   = threadIdx.x;
    const int blk = blockIdx.x;                // 0..2303
    const int b   = blk / (kL / 16);
    const int l0  = (blk % (kL / 16)) * 16;

    // stage seq tile [192 k][16 l]
    #pragma unroll
    for (int i = 0; i < 8; ++i) {
        int e  = i * 384 + t;                  // 0..3071
        int k  = e >> 4, li = e & 15;
        float v;
        if (k < 96) v = spatial[(size_t)(b * 96 + k) * kL + l0 + li];
        else        v = freq   [(size_t)(b * 96 + (k - 96)) * kL + l0 + li];
        sq[e] = v;
    }
    __syncthreads();

    const int co = t;
    float acc[16];
    {
        float bc = bias_c[co];
        #pragma unroll
        for (int i = 0; i < 16; ++i) acc[i] = bc;
    }
    const float4* sq4 = (const float4*)sq;
    const float* wp = WcT + co;
    for (int k = 0; k < 192; ++k) {
        float w = wp[k * 384];
        float4 a0 = sq4[k * 4 + 0];
        float4 a1 = sq4[k * 4 + 1];
        float4 a2 = sq4[k * 4 + 2];
        float4 a3 = sq4[k * 4 + 3];
        acc[0]  += w * a0.x;  acc[1]  += w * a0.y;  acc[2]  += w * a0.z;  acc[3]  += w * a0.w;
        acc[4]  += w * a1.x;  acc[5]  += w * a1.y;  acc[6]  += w * a1.z;  acc[7]  += w * a1.w;
        acc[8]  += w * a2.x;  acc[9]  += w * a2.y;  acc[10] += w * a2.z;  acc[11] += w * a2.w;
        acc[12] += w * a3.x;  acc[13] += w * a3.y;  acc[14] += w * a3.z;  acc[15] += w * a3.w;
    }
    const size_t rbase = (size_t)b * kL + l0;
    if (co < 192) {
        #pragma unroll
        for (int li = 0; li < 16; ++li) x_in[(rbase + li) * 192 + co] = acc[li];
    } else {
        #pragma unroll
        for (int li = 0; li < 16; ++li) z[(rbase + li) * 192 + (co - 192)] = acc[li];
    }
}

// ---------------------------------------------------------------------------
// K2: causal depthwise conv1d (width 4) + bias + SiLU. Thread per (row, d-vec4).
// ---------------------------------------------------------------------------
__global__ __launch_bounds__(256)
void k2_conv(const float* __restrict__ x_in, const float* __restrict__ conv_w,
             const float* __restrict__ conv_b, float* __restrict__ xc)
{
    int idx = blockIdx.x * 256 + threadIdx.x;
    if (idx >= kNROW * 48) return;
    const int d4 = idx % 48;
    const int r  = idx / 48;
    const int l  = r % kL;
    const int d0 = d4 * 4;
    float ax = 0.f, ay = 0.f, az = 0.f, aw = 0.f;
    #pragma unroll
    for (int k = 0; k < 4; ++k) {
        int li = l - 3 + k;
        if (li < 0) continue;
        const float4 xv = *(const float4*)&x_in[(size_t)(r - 3 + k) * 192 + d0];
        ax += xv.x * conv_w[(d0 + 0) * 4 + k];
        ay += xv.y * conv_w[(d0 + 1) * 4 + k];
        az += xv.z * conv_w[(d0 + 2) * 4 + k];
        aw += xv.w * conv_w[(d0 + 3) * 4 + k];
    }
    float4 o;
    o.x = silu_f(ax + conv_b[d0 + 0]);
    o.y = silu_f(ay + conv_b[d0 + 1]);
    o.z = silu_f(az + conv_b[d0 + 2]);
    o.w = silu_f(aw + conv_b[d0 + 3]);
    *(float4*)&xc[(size_t)r * 192 + d0] = o;
}

// ---------------------------------------------------------------------------
// K3: x_dbl = xc @ x_proj_w^T  (38 outputs/row).  dt -> dtr[row][6], B/C -> BC[row][32]
// ---------------------------------------------------------------------------
__global__ __launch_bounds__(256)
void k3_xproj(const float* __restrict__ xc, const float* __restrict__ x_proj_w,
              float* __restrict__ dtr, float* __restrict__ BC)
{
    int idx = blockIdx.x * 256 + threadIdx.x;
    if (idx >= kNROW * 38) return;
    const int j = idx % 38;
    const int r = idx / 38;
    const float4* xr = (const float4*)&xc[(size_t)r * 192];
    const float4* wr = (const float4*)&x_proj_w[j * 192];
    float acc = 0.f;
    #pragma unroll 4
    for (int k4 = 0; k4 < 48; ++k4) {
        float4 a = xr[k4], w = wr[k4];
        acc += a.x * w.x + a.y * w.y + a.z * w.z + a.w * w.w;
    }
    if (j < 6) dtr[(size_t)r * 6 + j] = acc;
    else       BC[(size_t)r * 32 + (j - 6)] = acc;
}

// ---------------------------------------------------------------------------
// K4: delta = softplus(dt @ dt_proj_w^T + dt_proj_b)
// ---------------------------------------------------------------------------
__global__ __launch_bounds__(256)
void k4_dt(const float* __restrict__ dtr, const float* __restrict__ dt_proj_w,
           const float* __restrict__ dt_proj_b, float* __restrict__ delta)
{
    int idx = blockIdx.x * 256 + threadIdx.x;
    if (idx >= kNROW * 192) return;
    const int d = idx % 192;
    const int r = idx / 192;
    float acc = dt_proj_b[d];
    #pragma unroll
    for (int j = 0; j < 6; ++j)
        acc += dtr[(size_t)r * 6 + j] * dt_proj_w[d * 6 + j];
    float sp = (acc > 20.f) ? acc : log1pf(expf(acc));
    delta[(size_t)r * 192 + d] = sp;
}

// ---------------------------------------------------------------------------
// K5: scan pass 1 — per (b, d-group-of-4, chunk) wave. lane = (ld,s) = 4x16.
// Computes chunk affine transfer: h_out = P*h_in + S.
// ---------------------------------------------------------------------------
__global__ __launch_bounds__(256)
void k5_scan1(const float* __restrict__ delta, const float* __restrict__ xc,
              const float* __restrict__ BC, const float* __restrict__ A,
              float* __restrict__ Pc, float* __restrict__ Sc)
{
    const int wid  = (blockIdx.x * 256 + threadIdx.x) >> 6;   // 0..13823
    const int lane = threadIdx.x & 63;
    const int c  = wid % kNC;
    const int dg = (wid / kNC) % 48;
    const int b  = wid / (kNC * 48);
    const int s  = lane & 15;
    const int d  = dg * 4 + (lane >> 4);
    const float Ads = A[dg * 64 + lane];

    const size_t rbase = (size_t)b * kL + (size_t)c * kCL;
    const float* dp = delta + rbase * 192 + d;
    const float* xp = xc    + rbase * 192 + d;
    const float* bp = BC    + rbase * 32  + s;

    float P = 1.f, S = 0.f;
    #pragma unroll 4
    for (int i = 0; i < kCL; ++i) {
        float dv = *dp, xv = *xp, bv = *bp;
        float a  = __expf(dv * Ads);
        float bt = dv * xv * bv;
        P *= a;
        S  = a * S + bt;
        dp += 192; xp += 192; bp += 32;
    }
    const int row = (b * 192 + d) * 16 + s;
    Pc[(size_t)c * kNSEQ + row] = P;
    Sc[(size_t)c * kNSEQ + row] = S;
}

// ---------------------------------------------------------------------------
// K6: exclusive scan over chunk transfers, per (b,d,s) thread.
// ---------------------------------------------------------------------------
__global__ __launch_bounds__(256)
void k6_cscan(const float* __restrict__ Pc, const float* __restrict__ Sc,
              float* __restrict__ hin)
{
    const int row = blockIdx.x * 256 + threadIdx.x;   // < 12288
    float h = 0.f;
    for (int c = 0; c < kNC; ++c) {
        size_t o = (size_t)c * kNSEQ + row;
        hin[o] = h;
        h = Pc[o] * h + Sc[o];
    }
}

// ---------------------------------------------------------------------------
// K7: scan pass 2 — replay with correct h_in, emit y[l][d] = sum_s h*C.
// ---------------------------------------------------------------------------
__global__ __launch_bounds__(256)
void k7_scan2(const float* __restrict__ delta, const float* __restrict__ xc,
              const float* __restrict__ BC, const float* __restrict__ A,
              const float* __restrict__ hin, float* __restrict__ ys)
{
    const int wid  = (blockIdx.x * 256 + threadIdx.x) >> 6;
    const int lane = threadIdx.x & 63;
    const int c  = wid % kNC;
    const int dg = (wid / kNC) % 48;
    const int b  = wid / (kNC * 48);
    const int s  = lane & 15;
    const int d  = dg * 4 + (lane >> 4);
    const float Ads = A[dg * 64 + lane];
    const int row = (b * 192 + d) * 16 + s;

    const size_t rbase = (size_t)b * kL + (size_t)c * kCL;
    const float* dp = delta + rbase * 192 + d;
    const float* xp = xc    + rbase * 192 + d;
    const float* bp = BC    + rbase * 32  + s;
    const float* cp = BC    + rbase * 32  + 16 + s;
    float*       yp = ys    + rbase * 192 + d;

    float h = hin[(size_t)c * kNSEQ + row];
    for (int i = 0; i < kCL; ++i) {
        float dv = *dp, xv = *xp, bv = *bp, cv = *cp;
        float a = __expf(dv * Ads);
        h = a * h + dv * xv * bv;
        float pv = h * cv;
        pv += __shfl_xor(pv, 1);
        pv += __shfl_xor(pv, 2);
        pv += __shfl_xor(pv, 4);
        pv += __shfl_xor(pv, 8);
        if (s == 0) *yp = pv;
        dp += 192; xp += 192; bp += 32; cp += 32; yp += 192;
    }
}

// ---------------------------------------------------------------------------
// K8: y = (ys + xc*D) * silu(z); mixed = y @ out_proj_w^T; LayerNorm(C=96);
//     out[b,c,l] = normed + spatial[b,c,l].  32 rows per block.
// ---------------------------------------------------------------------------
__global__ __launch_bounds__(256)
void k8_final(const float* __restrict__ ys, const float* __restrict__ xc,
              const float* __restrict__ z, const float* __restrict__ Dp,
              const float* __restrict__ out_proj_w, const float* __restrict__ ln_g,
              const float* __restrict__ ln_b, const float* __restrict__ spatial,
              float* __restrict__ out)
{
    __shared__ float yt[32 * 196];      // padded stride 196
    __shared__ float wt[96 * 36];       // W chunk [96 c][32 k], padded stride 36
    const int t = threadIdx.x;
    const size_t r0 = (size_t)blockIdx.x * 32;
    const int b = (int)(r0 / kL);

    // stage gated y tile
    #pragma unroll
    for (int i = 0; i < 6; ++i) {
        int e  = i * 256 + t;           // vec4 index over 32*48
        int l  = e / 48, d4 = e % 48;
        size_t r = r0 + l;
        float4 yv = *(const float4*)&ys[r * 192 + d4 * 4];
        float4 xv = *(const float4*)&xc[r * 192 + d4 * 4];
        float4 zv = *(const float4*)&z [r * 192 + d4 * 4];
        float4 Dv = *(const float4*)&Dp[d4 * 4];
        float4 o;
        o.x = (yv.x + xv.x * Dv.x) * silu_f(zv.x);
        o.y = (yv.y + xv.y * Dv.y) * silu_f(zv.y);
        o.z = (yv.z + xv.z * Dv.z) * silu_f(zv.z);
        o.w = (yv.w + xv.w * Dv.w) * silu_f(zv.w);
        *(float4*)&yt[l * 196 + d4 * 4] = o;
    }
    __syncthreads();

    const int l  = t >> 3;
    const int cg = t & 7;
    float acc[12];
    #pragma unroll
    for (int i = 0; i < 12; ++i) acc[i] = 0.f;

    for (int kc = 0; kc < 6; ++kc) {
        __syncthreads();  // previous chunk's wt reads complete
        #pragma unroll
        for (int i = 0; i < 3; ++i) {
            int e = i * 256 + t;        // vec4 index over 96*8
            int c = e / 8, k4 = e % 8;
            float4 w = *(const float4*)&out_proj_w[c * 192 + kc * 32 + k4 * 4];
            *(float4*)&wt[c * 36 + k4 * 4] = w;
        }
        __syncthreads();
        #pragma unroll
        for (int k4 = 0; k4 < 8; ++k4) {
            float4 yv = *(const float4*)&yt[l * 196 + kc * 32 + k4 * 4];
            #pragma unroll
            for (int i = 0; i < 12; ++i) {
                const float4 wv = *(const float4*)&wt[(cg + 8 * i) * 36 + k4 * 4];
                acc[i] += yv.x * wv.x + yv.y * wv.y + yv.z * wv.z + yv.w * wv.w;
            }
        }
    }

    // LayerNorm over 96 channels (partials live in 8 lanes sharing l)
    float sum = 0.f, ss = 0.f;
    #pragma unroll
    for (int i = 0; i < 12; ++i) { sum += acc[i]; ss += acc[i] * acc[i]; }
    #pragma unroll
    for (int m = 1; m < 8; m <<= 1) {
        sum += __shfl_xor(sum, m);
        ss  += __shfl_xor(ss, m);
    }
    const float mu  = sum * (1.f / 96.f);
    const float var = ss * (1.f / 96.f) - mu * mu;
    const float rs  = rsqrtf(var + 1e-5f);
    const int lg = (int)(r0 % kL) + l;
    #pragma unroll
    for (int i = 0; i < 12; ++i) {
        int c = cg + 8 * i;
        float nv = (acc[i] - mu) * rs * ln_g[c] + ln_b[c];
        size_t o = ((size_t)b * 96 + c) * kL + lg;
        out[o] = nv + spatial[o];
    }
}

// ---------------------------------------------------------------------------
extern "C" void kernel_launch(void* const* d_in, const int* in_sizes, int n_in,
                              void* d_out, int out_size, void* d_ws, size_t ws_size,
                              hipStream_t stream) {
    const float* spatial    = (const float*)d_in[0];
    const float* freq       = (const float*)d_in[1];
    const float* proj_w     = (const float*)d_in[2];
    const float* proj_b     = (const float*)d_in[3];
    const float* in_proj_w  = (const float*)d_in[4];
    const float* conv_w     = (const float*)d_in[5];
    const float* conv_b     = (const float*)d_in[6];
    const float* x_proj_w   = (const float*)d_in[7];
    const float* dt_proj_w  = (const float*)d_in[8];
    const float* dt_proj_b  = (const float*)d_in[9];
    const float* A_log      = (const float*)d_in[10];
    const float* D_param    = (const float*)d_in[11];
    const float* out_proj_w = (const float*)d_in[12];
    const float* ln_g       = (const float*)d_in[13];
    const float* ln_b       = (const float*)d_in[14];
    float* out = (float*)d_out;

    char* wsb = (char*)d_ws;
    size_t off = 0;
    auto alloc = [&](size_t bytes) -> float* {
        float* p = (float*)(wsb + off);
        off += (bytes + 255) & ~(size_t)255;
        return p;
    };
    float* x_in  = alloc((size_t)kNROW * kDI * 4);   // 28.3 MB (reused as ys)
    float* z     = alloc((size_t)kNROW * kDI * 4);
    float* xc    = alloc((size_t)kNROW * kDI * 4);
    float* delta = alloc((size_t)kNROW * kDI * 4);
    float* dtr   = alloc((size_t)kNROW * kDTR * 4);
    float* BC    = alloc((size_t)kNROW * 32 * 4);
    float* Pc    = alloc((size_t)kNC * kNSEQ * 4);
    float* Sc    = alloc((size_t)kNC * kNSEQ * 4);
    float* hin   = alloc((size_t)kNC * kNSEQ * 4);
    float* WcT   = alloc((size_t)192 * 384 * 4);
    float* biasc = alloc(384 * 4);
    float* Aa    = alloc((size_t)kDI * kDS * 4);
    float* ys    = x_in;  // x_in dead after k2_conv

    k0_prep <<<288,  256, 0, stream>>>(proj_w, proj_b, in_proj_w, A_log, WcT, biasc, Aa);
    k1_xz   <<<2304, 384, 0, stream>>>(spatial, freq, WcT, biasc, x_in, z);
    k2_conv <<<6912, 256, 0, stream>>>(x_in, conv_w, conv_b, xc);
    k3_xproj<<<5472, 256, 0, stream>>>(xc, x_proj_w, dtr, BC);
    k4_dt   <<<27648,256, 0, stream>>>(dtr, dt_proj_w, dt_proj_b, delta);
    k5_scan1<<<3456, 256, 0, stream>>>(delta, xc, BC, Aa, Pc, Sc);
    k6_cscan<<<48,   256, 0, stream>>>(Pc, Sc, hin);
    k7_scan2<<<3456, 256, 0, stream>>>(delta, xc, BC, Aa, hin, ys);
    k8_final<<<1152, 256, 0, stream>>>(ys, xc, z, D_param, out_proj_w, ln_g, ln_b, spatial, out);
}

// Round 4
// 557.321 us; speedup vs baseline: 1.1929x; 1.1929x over previous
//
#include <hip/hip_runtime.h>
#include <math.h>

// Problem constants (B,C,H,W = 4,96,96,96)
#define kC    96
#define kL    9216          // H*W
#define kB    4
#define kDI   192           // d_inner
#define kDS   16            // d_state
#define kDTR  6             // dt_rank
#define kCL   128           // scan chunk length
#define kNC   72            // chunks per sequence (72*128 = 9216)
#define kNROW (kB*kL)       // 36864 rows
#define kNSEQ (kB*kDI*kDS)  // 12288 independent scalar recurrences

__device__ __forceinline__ float silu_f(float v) { return v / (1.f + expf(-v)); }

// ---------------------------------------------------------------------------
// K0: precompute WcT[k][co] = sum_c in_proj_w[co][c]*proj_w[c][k]  (k<192, co<384)
//     bias_c[co] = in_proj_w[co] . proj_b ;  A[d][s] = -exp(A_log[d][s])
// ---------------------------------------------------------------------------
__global__ __launch_bounds__(256)
void k0_prep(const float* __restrict__ proj_w, const float* __restrict__ proj_b,
             const float* __restrict__ in_proj_w, const float* __restrict__ A_log,
             float* __restrict__ WcT, float* __restrict__ bias_c, float* __restrict__ A)
{
    int idx = blockIdx.x * 256 + threadIdx.x;
    if (idx < 384 * 192) {
        int co = idx / 192;
        int k  = idx % 192;
        float acc = 0.f;
        #pragma unroll 4
        for (int c = 0; c < 96; ++c)
            acc += in_proj_w[co * 96 + c] * proj_w[c * 192 + k];
        WcT[k * 384 + co] = acc;
    }
    if (idx < 384) {
        float acc = 0.f;
        for (int c = 0; c < 96; ++c) acc += in_proj_w[idx * 96 + c] * proj_b[c];
        bias_c[idx] = acc;
    }
    if (idx < kDI * kDS) {
        A[idx] = -expf(A_log[idx]);
    }
}

// ---------------------------------------------------------------------------
// K1: xz = seq @ WcT + bias.  Register-blocked: block tile 32 l x 384 co,
// thread = 6 co (stride 64) x 8 l. Per k: 2 broadcast ds_b128 + 6 coalesced
// W loads + 48 v_fmac -> VALU-bound.
// ---------------------------------------------------------------------------
__global__ __launch_bounds__(256)
void k1_xz(const float* __restrict__ spatial, const float* __restrict__ freq,
           const float* __restrict__ WcT, const float* __restrict__ bias_c,
           float* __restrict__ x_in, float* __restrict__ z)
{
    __shared__ float As[192 * 36];         // [k][32 l], stride 36 (pad)
    const int t   = threadIdx.x;
    const int blk = blockIdx.x;            // 0..1151
    const int b   = blk / 288;
    const int l0  = (blk % 288) * 32;

    // stage A tile: 192 k x 32 l
    #pragma unroll
    for (int i = 0; i < 6; ++i) {
        int e  = i * 256 + t;              // 0..1535 (float4 units)
        int k  = e >> 3, lg = e & 7;
        const float* src = (k < 96)
            ? &spatial[(size_t)(b * 96 + k) * kL]
            : &freq   [(size_t)(b * 96 + (k - 96)) * kL];
        float4 v = *(const float4*)&src[l0 + lg * 4];
        *(float4*)&As[k * 36 + lg * 4] = v;
    }
    __syncthreads();

    const int w    = t >> 6;               // wave -> l-slice of 8
    const int lane = t & 63;
    float acc[6][8];
    #pragma unroll
    for (int i = 0; i < 6; ++i) {
        float bc = bias_c[lane + 64 * i];
        #pragma unroll
        for (int l = 0; l < 8; ++l) acc[i][l] = bc;
    }

    const float* wp = WcT + lane;
    #pragma unroll 2
    for (int k = 0; k < 192; ++k) {
        const float4 a0 = *(const float4*)&As[k * 36 + w * 8];
        const float4 a1 = *(const float4*)&As[k * 36 + w * 8 + 4];
        float wv[6];
        #pragma unroll
        for (int i = 0; i < 6; ++i) wv[i] = wp[k * 384 + 64 * i];
        #pragma unroll
        for (int i = 0; i < 6; ++i) {
            acc[i][0] += wv[i] * a0.x;  acc[i][1] += wv[i] * a0.y;
            acc[i][2] += wv[i] * a0.z;  acc[i][3] += wv[i] * a0.w;
            acc[i][4] += wv[i] * a1.x;  acc[i][5] += wv[i] * a1.y;
            acc[i][6] += wv[i] * a1.z;  acc[i][7] += wv[i] * a1.w;
        }
    }

    const size_t rbase = (size_t)b * kL + l0 + w * 8;
    #pragma unroll
    for (int l = 0; l < 8; ++l) {
        const size_t ro = (rbase + l) * 192;
        #pragma unroll
        for (int i = 0; i < 3; ++i)
            x_in[ro + lane + 64 * i] = acc[i][l];
        #pragma unroll
        for (int i = 3; i < 6; ++i)
            z[ro + lane + 64 * i - 192] = acc[i][l];
    }
}

// ---------------------------------------------------------------------------
// K2: causal depthwise conv1d (width 4) + bias + SiLU. Thread per (row, d-vec4).
// ---------------------------------------------------------------------------
__global__ __launch_bounds__(256)
void k2_conv(const float* __restrict__ x_in, const float* __restrict__ conv_w,
             const float* __restrict__ conv_b, float* __restrict__ xc)
{
    int idx = blockIdx.x * 256 + threadIdx.x;
    if (idx >= kNROW * 48) return;
    const int d4 = idx % 48;
    const int r  = idx / 48;
    const int l  = r % kL;
    const int d0 = d4 * 4;
    float ax = 0.f, ay = 0.f, az = 0.f, aw = 0.f;
    #pragma unroll
    for (int k = 0; k < 4; ++k) {
        int li = l - 3 + k;
        if (li < 0) continue;
        const float4 xv = *(const float4*)&x_in[(size_t)(r - 3 + k) * 192 + d0];
        ax += xv.x * conv_w[(d0 + 0) * 4 + k];
        ay += xv.y * conv_w[(d0 + 1) * 4 + k];
        az += xv.z * conv_w[(d0 + 2) * 4 + k];
        aw += xv.w * conv_w[(d0 + 3) * 4 + k];
    }
    float4 o;
    o.x = silu_f(ax + conv_b[d0 + 0]);
    o.y = silu_f(ay + conv_b[d0 + 1]);
    o.z = silu_f(az + conv_b[d0 + 2]);
    o.w = silu_f(aw + conv_b[d0 + 3]);
    *(float4*)&xc[(size_t)r * 192 + d0] = o;
}

// ---------------------------------------------------------------------------
// K34: fused x_proj + dt_proj + softplus. Block = 64 rows.
// xcT[k][r] in LDS (stride 65, conflict-free b32 with lane=r); x_proj rows
// as wave-uniform scalar loads (10 j per wave). Then delta = softplus(dt@W+b)
// computed in-block; all global writes coalesced via LDS transpose.
// ---------------------------------------------------------------------------
__global__ __launch_bounds__(256)
void k34(const float* __restrict__ xc, const float* __restrict__ x_proj_w,
         const float* __restrict__ dt_proj_w, const float* __restrict__ dt_proj_b,
         float* __restrict__ BC, float* __restrict__ delta)
{
    __shared__ float xcT[192 * 65];     // [k][r], later reused as deltaT[d][r]
    __shared__ float bc_s[64 * 33];     // [r][32 j]
    __shared__ float dtr_s[64 * 9];     // [r][6 dt]
    const int t = threadIdx.x;
    const size_t R0 = (size_t)blockIdx.x * 64;

    // stage xc transposed
    #pragma unroll
    for (int i = 0; i < 12; ++i) {
        int e = i * 256 + t;            // 0..3071
        int r = e / 48, k4 = e % 48;
        float4 v = *(const float4*)&xc[(R0 + r) * 192 + k4 * 4];
        xcT[(k4 * 4 + 0) * 65 + r] = v.x;
        xcT[(k4 * 4 + 1) * 65 + r] = v.y;
        xcT[(k4 * 4 + 2) * 65 + r] = v.z;
        xcT[(k4 * 4 + 3) * 65 + r] = v.w;
    }
    __syncthreads();

    const int lane = t & 63;
    const int w = __builtin_amdgcn_readfirstlane(t >> 6);  // uniform wave id

    // x_dbl: wave w computes j in {w, w+4, ..., w+36} for all 64 rows
    float acc[10];
    #pragma unroll
    for (int i = 0; i < 10; ++i) acc[i] = 0.f;
    int jj[10];
    #pragma unroll
    for (int i = 0; i < 10; ++i) { int j = w + 4 * i; jj[i] = (j < 38) ? j : 37; }

    #pragma unroll 4
    for (int k = 0; k < 192; ++k) {
        const float xv = xcT[k * 65 + lane];
        #pragma unroll
        for (int i = 0; i < 10; ++i)
            acc[i] += xv * x_proj_w[jj[i] * 192 + k];   // scalar (uniform) load
    }

    // scatter results to LDS
    #pragma unroll
    for (int i = 0; i < 10; ++i) {
        int j = w + 4 * i;
        if (j < 6)       dtr_s[lane * 9 + j] = acc[i];
        else if (j < 38) bc_s[lane * 33 + (j - 6)] = acc[i];
    }
    __syncthreads();

    // BC coalesced writeout
    #pragma unroll
    for (int i = 0; i < 2; ++i) {
        int e = i * 256 + t;            // 0..511
        int r = e >> 3, j4 = e & 7;
        float4 v;
        v.x = bc_s[r * 33 + j4 * 4 + 0];
        v.y = bc_s[r * 33 + j4 * 4 + 1];
        v.z = bc_s[r * 33 + j4 * 4 + 2];
        v.w = bc_s[r * 33 + j4 * 4 + 3];
        *(float4*)&BC[(R0 + r) * 32 + j4 * 4] = v;
    }

    // delta = softplus(dt @ dt_proj_w^T + b): wave w covers d in [w*48, w*48+48)
    {
        float dtv[6];
        #pragma unroll
        for (int j = 0; j < 6; ++j) dtv[j] = dtr_s[lane * 9 + j];
        #pragma unroll 4
        for (int m = 0; m < 48; ++m) {
            const int d = w * 48 + m;   // uniform
            float a = dt_proj_b[d];
            #pragma unroll
            for (int j = 0; j < 6; ++j) a += dtv[j] * dt_proj_w[d * 6 + j];
            float sp = (a > 20.f) ? a : log1pf(expf(a));
            xcT[d * 65 + lane] = sp;    // deltaT[d][r]
        }
    }
    __syncthreads();

    // delta coalesced writeout
    #pragma unroll
    for (int i = 0; i < 12; ++i) {
        int e = i * 256 + t;
        int r = e / 48, d4 = e % 48;
        float4 v;
        v.x = xcT[(d4 * 4 + 0) * 65 + r];
        v.y = xcT[(d4 * 4 + 1) * 65 + r];
        v.z = xcT[(d4 * 4 + 2) * 65 + r];
        v.w = xcT[(d4 * 4 + 3) * 65 + r];
        *(float4*)&delta[(R0 + r) * 192 + d4 * 4] = v;
    }
}

// ---------------------------------------------------------------------------
// K5: scan pass 1 — per (b, d-group-of-4, chunk) wave. lane = (ld,s) = 4x16.
// Computes chunk affine transfer: h_out = P*h_in + S.
// ---------------------------------------------------------------------------
__global__ __launch_bounds__(256)
void k5_scan1(const float* __restrict__ delta, const float* __restrict__ xc,
              const float* __restrict__ BC, const float* __restrict__ A,
              float* __restrict__ Pc, float* __restrict__ Sc)
{
    const int wid  = (blockIdx.x * 256 + threadIdx.x) >> 6;   // 0..13823
    const int lane = threadIdx.x & 63;
    const int c  = wid % kNC;
    const int dg = (wid / kNC) % 48;
    const int b  = wid / (kNC * 48);
    const int s  = lane & 15;
    const int d  = dg * 4 + (lane >> 4);
    const float Ads = A[dg * 64 + lane];

    const size_t rbase = (size_t)b * kL + (size_t)c * kCL;
    const float* dp = delta + rbase * 192 + d;
    const float* xp = xc    + rbase * 192 + d;
    const float* bp = BC    + rbase * 32  + s;

    float P = 1.f, S = 0.f;
    #pragma unroll 4
    for (int i = 0; i < kCL; ++i) {
        float dv = *dp, xv = *xp, bv = *bp;
        float a  = __expf(dv * Ads);
        float bt = dv * xv * bv;
        P *= a;
        S  = a * S + bt;
        dp += 192; xp += 192; bp += 32;
    }
    const int row = (b * 192 + d) * 16 + s;
    Pc[(size_t)c * kNSEQ + row] = P;
    Sc[(size_t)c * kNSEQ + row] = S;
}

// ---------------------------------------------------------------------------
// K6: exclusive scan over chunk transfers, per (b,d,s) thread.
// ---------------------------------------------------------------------------
__global__ __launch_bounds__(256)
void k6_cscan(const float* __restrict__ Pc, const float* __restrict__ Sc,
              float* __restrict__ hin)
{
    const int row = blockIdx.x * 256 + threadIdx.x;   // < 12288
    float h = 0.f;
    for (int c = 0; c < kNC; ++c) {
        size_t o = (size_t)c * kNSEQ + row;
        hin[o] = h;
        h = Pc[o] * h + Sc[o];
    }
}

// ---------------------------------------------------------------------------
// K7: scan pass 2 — replay with correct h_in, emit y[l][d] = sum_s h*C.
// ---------------------------------------------------------------------------
__global__ __launch_bounds__(256)
void k7_scan2(const float* __restrict__ delta, const float* __restrict__ xc,
              const float* __restrict__ BC, const float* __restrict__ A,
              const float* __restrict__ hin, float* __restrict__ ys)
{
    const int wid  = (blockIdx.x * 256 + threadIdx.x) >> 6;
    const int lane = threadIdx.x & 63;
    const int c  = wid % kNC;
    const int dg = (wid / kNC) % 48;
    const int b  = wid / (kNC * 48);
    const int s  = lane & 15;
    const int d  = dg * 4 + (lane >> 4);
    const float Ads = A[dg * 64 + lane];
    const int row = (b * 192 + d) * 16 + s;

    const size_t rbase = (size_t)b * kL + (size_t)c * kCL;
    const float* dp = delta + rbase * 192 + d;
    const float* xp = xc    + rbase * 192 + d;
    const float* bp = BC    + rbase * 32  + s;
    const float* cp = BC    + rbase * 32  + 16 + s;
    float*       yp = ys    + rbase * 192 + d;

    float h = hin[(size_t)c * kNSEQ + row];
    for (int i = 0; i < kCL; ++i) {
        float dv = *dp, xv = *xp, bv = *bp, cv = *cp;
        float a = __expf(dv * Ads);
        h = a * h + dv * xv * bv;
        float pv = h * cv;
        pv += __shfl_xor(pv, 1);
        pv += __shfl_xor(pv, 2);
        pv += __shfl_xor(pv, 4);
        pv += __shfl_xor(pv, 8);
        if (s == 0) *yp = pv;
        dp += 192; xp += 192; bp += 32; cp += 32; yp += 192;
    }
}

// ---------------------------------------------------------------------------
// K8: y = (ys + xc*D) * silu(z); mixed = y @ out_proj_w^T; LayerNorm(C=96);
//     out[b,c,l] = normed + spatial[b,c,l].  32 rows per block.
// ---------------------------------------------------------------------------
__global__ __launch_bounds__(256)
void k8_final(const float* __restrict__ ys, const float* __restrict__ xc,
              const float* __restrict__ z, const float* __restrict__ Dp,
              const float* __restrict__ out_proj_w, const float* __restrict__ ln_g,
              const float* __restrict__ ln_b, const float* __restrict__ spatial,
              float* __restrict__ out)
{
    __shared__ float yt[32 * 196];      // padded stride 196
    __shared__ float wt[96 * 36];       // W chunk [96 c][32 k], padded stride 36
    const int t = threadIdx.x;
    const size_t r0 = (size_t)blockIdx.x * 32;
    const int b = (int)(r0 / kL);

    // stage gated y tile
    #pragma unroll
    for (int i = 0; i < 6; ++i) {
        int e  = i * 256 + t;           // vec4 index over 32*48
        int l  = e / 48, d4 = e % 48;
        size_t r = r0 + l;
        float4 yv = *(const float4*)&ys[r * 192 + d4 * 4];
        float4 xv = *(const float4*)&xc[r * 192 + d4 * 4];
        float4 zv = *(const float4*)&z [r * 192 + d4 * 4];
        float4 Dv = *(const float4*)&Dp[d4 * 4];
        float4 o;
        o.x = (yv.x + xv.x * Dv.x) * silu_f(zv.x);
        o.y = (yv.y + xv.y * Dv.y) * silu_f(zv.y);
        o.z = (yv.z + xv.z * Dv.z) * silu_f(zv.z);
        o.w = (yv.w + xv.w * Dv.w) * silu_f(zv.w);
        *(float4*)&yt[l * 196 + d4 * 4] = o;
    }
    __syncthreads();

    const int l  = t >> 3;
    const int cg = t & 7;
    float acc[12];
    #pragma unroll
    for (int i = 0; i < 12; ++i) acc[i] = 0.f;

    for (int kc = 0; kc < 6; ++kc) {
        __syncthreads();  // previous chunk's wt reads complete
        #pragma unroll
        for (int i = 0; i < 3; ++i) {
            int e = i * 256 + t;        // vec4 index over 96*8
            int c = e / 8, k4 = e % 8;
            float4 w = *(const float4*)&out_proj_w[c * 192 + kc * 32 + k4 * 4];
            *(float4*)&wt[c * 36 + k4 * 4] = w;
        }
        __syncthreads();
        #pragma unroll
        for (int k4 = 0; k4 < 8; ++k4) {
            float4 yv = *(const float4*)&yt[l * 196 + kc * 32 + k4 * 4];
            #pragma unroll
            for (int i = 0; i < 12; ++i) {
                const float4 wv = *(const float4*)&wt[(cg + 8 * i) * 36 + k4 * 4];
                acc[i] += yv.x * wv.x + yv.y * wv.y + yv.z * wv.z + yv.w * wv.w;
            }
        }
    }

    // LayerNorm over 96 channels (partials live in 8 lanes sharing l)
    float sum = 0.f, ss = 0.f;
    #pragma unroll
    for (int i = 0; i < 12; ++i) { sum += acc[i]; ss += acc[i] * acc[i]; }
    #pragma unroll
    for (int m = 1; m < 8; m <<= 1) {
        sum += __shfl_xor(sum, m);
        ss  += __shfl_xor(ss, m);
    }
    const float mu  = sum * (1.f / 96.f);
    const float var = ss * (1.f / 96.f) - mu * mu;
    const float rs  = rsqrtf(var + 1e-5f);
    const int lg = (int)(r0 % kL) + l;
    #pragma unroll
    for (int i = 0; i < 12; ++i) {
        int c = cg + 8 * i;
        float nv = (acc[i] - mu) * rs * ln_g[c] + ln_b[c];
        size_t o = ((size_t)b * 96 + c) * kL + lg;
        out[o] = nv + spatial[o];
    }
}

// ---------------------------------------------------------------------------
extern "C" void kernel_launch(void* const* d_in, const int* in_sizes, int n_in,
                              void* d_out, int out_size, void* d_ws, size_t ws_size,
                              hipStream_t stream) {
    const float* spatial    = (const float*)d_in[0];
    const float* freq       = (const float*)d_in[1];
    const float* proj_w     = (const float*)d_in[2];
    const float* proj_b     = (const float*)d_in[3];
    const float* in_proj_w  = (const float*)d_in[4];
    const float* conv_w     = (const float*)d_in[5];
    const float* conv_b     = (const float*)d_in[6];
    const float* x_proj_w   = (const float*)d_in[7];
    const float* dt_proj_w  = (const float*)d_in[8];
    const float* dt_proj_b  = (const float*)d_in[9];
    const float* A_log      = (const float*)d_in[10];
    const float* D_param    = (const float*)d_in[11];
    const float* out_proj_w = (const float*)d_in[12];
    const float* ln_g       = (const float*)d_in[13];
    const float* ln_b       = (const float*)d_in[14];
    float* out = (float*)d_out;

    char* wsb = (char*)d_ws;
    size_t off = 0;
    auto alloc = [&](size_t bytes) -> float* {
        float* p = (float*)(wsb + off);
        off += (bytes + 255) & ~(size_t)255;
        return p;
    };
    float* x_in  = alloc((size_t)kNROW * kDI * 4);   // 28.3 MB (reused as ys)
    float* z     = alloc((size_t)kNROW * kDI * 4);
    float* xc    = alloc((size_t)kNROW * kDI * 4);
    float* delta = alloc((size_t)kNROW * kDI * 4);
    float* BC    = alloc((size_t)kNROW * 32 * 4);
    float* Pc    = alloc((size_t)kNC * kNSEQ * 4);
    float* Sc    = alloc((size_t)kNC * kNSEQ * 4);
    float* hin   = alloc((size_t)kNC * kNSEQ * 4);
    float* WcT   = alloc((size_t)192 * 384 * 4);
    float* biasc = alloc(384 * 4);
    float* Aa    = alloc((size_t)kDI * kDS * 4);
    float* ys    = x_in;  // x_in dead after k2_conv

    k0_prep <<<288,  256, 0, stream>>>(proj_w, proj_b, in_proj_w, A_log, WcT, biasc, Aa);
    k1_xz   <<<1152, 256, 0, stream>>>(spatial, freq, WcT, biasc, x_in, z);
    k2_conv <<<6912, 256, 0, stream>>>(x_in, conv_w, conv_b, xc);
    k34     <<<576,  256, 0, stream>>>(xc, x_proj_w, dt_proj_w, dt_proj_b, BC, delta);
    k5_scan1<<<3456, 256, 0, stream>>>(delta, xc, BC, Aa, Pc, Sc);
    k6_cscan<<<48,   256, 0, stream>>>(Pc, Sc, hin);
    k7_scan2<<<3456, 256, 0, stream>>>(delta, xc, BC, Aa, hin, ys);
    k8_final<<<1152, 256, 0, stream>>>(ys, xc, z, D_param, out_proj_w, ln_g, ln_b, spatial, out);
}